// Round 2
// baseline (730.774 us; speedup 1.0000x reference)
//
#include <hip/hip_runtime.h>
#include <hip/hip_cooperative_groups.h>

namespace cg = cooperative_groups;

#define NTOK 4096
#define DIN  4096
#define DOUT 4096

typedef short bf16x8 __attribute__((ext_vector_type(8)));
typedef float f32x4  __attribute__((ext_vector_type(4)));

__device__ __forceinline__ unsigned short f2bf(float f) {
    union { float f; unsigned u; } v; v.f = f;
    unsigned r = v.u + 0x7FFFu + ((v.u >> 16) & 1u);
    return (unsigned short)(r >> 16);
}

__device__ __forceinline__ void async_copy16(const void* g, void* l) {
    __builtin_amdgcn_global_load_lds(
        (const __attribute__((address_space(1))) unsigned int*)g,
        (__attribute__((address_space(3))) unsigned int*)l, 16, 0, 0);
}

// ---------------- fused scale + w_eff (no fp64 divide: |w| >= 0.5*sc comparison) -------------
// clip(rint(w/sc),-1,1)*sc  ==  (|w| >= 0.5*sc) ? copysign(sc, w) : 0   for sc > 0
// (identical in fp64 except exact ties, measure-zero). One block per row; w kept in registers.
__global__ void weff_kernel(const float* __restrict__ w, const float* __restrict__ fast,
                            const float* __restrict__ slow, unsigned short* __restrict__ weff) {
    int row = blockIdx.x;
    int t = threadIdx.x;                                  // 256 threads
    const float4* wr = (const float4*)(w + (size_t)row * DIN);
    const float4* fr = (const float4*)(fast + (size_t)row * DIN);
    const float4* sr = (const float4*)(slow + (size_t)row * DIN);
    ushort4* ow = (ushort4*)(weff + (size_t)row * DIN);

    float4 wv[4];
    double s = 0.0;
    #pragma unroll
    for (int u = 0; u < 4; ++u) {
        wv[u] = wr[t + u * 256];
        s += (double)fabsf(wv[u].x) + (double)fabsf(wv[u].y)
           + (double)fabsf(wv[u].z) + (double)fabsf(wv[u].w);
    }
    for (int o = 32; o > 0; o >>= 1) s += __shfl_down(s, o);
    __shared__ double part[4];
    __shared__ double scLds;
    int wave = t >> 6, lane = t & 63;
    if (lane == 0) part[wave] = s;
    __syncthreads();
    if (t == 0) scLds = fmax((part[0] + part[1] + part[2] + part[3]) * (1.0 / DIN), 1e-5);
    __syncthreads();
    double scd = scLds;
    double hs = 0.5 * scd;

    #pragma unroll
    for (int u = 0; u < 4; ++u) {
        float4 fv = fr[t + u * 256];
        float4 sv = sr[t + u * 256];
        float4 wq = wv[u];
        ushort4 o;
        o.x = f2bf((float)((((double)fabsf(wq.x) >= hs) ? copysign(scd, (double)wq.x) : 0.0)
                           + 0.1 * (double)fv.x + 0.05 * (double)sv.x));
        o.y = f2bf((float)((((double)fabsf(wq.y) >= hs) ? copysign(scd, (double)wq.y) : 0.0)
                           + 0.1 * (double)fv.y + 0.05 * (double)sv.y));
        o.z = f2bf((float)((((double)fabsf(wq.z) >= hs) ? copysign(scd, (double)wq.z) : 0.0)
                           + 0.1 * (double)fv.z + 0.05 * (double)sv.z));
        o.w = f2bf((float)((((double)fabsf(wq.w) >= hs) ? copysign(scd, (double)wq.w) : 0.0)
                           + 0.1 * (double)fv.w + 0.05 * (double)sv.w));
        ow[t + u * 256] = o;
    }
}

// ---------------- x -> x_bf16 (row-major) + xT bf16, vectorized 64x64 tiles -----------------
__global__ void transpose_kernel(const float* __restrict__ x, unsigned short* __restrict__ xbf,
                                 unsigned short* __restrict__ xT) {
    __shared__ unsigned short tile[64][72];
    int bi = blockIdx.y, bj = blockIdx.x;   // 64-row x 64-col tile
    int t = threadIdx.x;                    // 256
    // load/convert phase: thread handles float4 idx {t, t+256, t+512, t+768} of the tile
    int c4 = t & 15, r0 = t >> 4;
    #pragma unroll
    for (int u = 0; u < 4; ++u) {
        int r = r0 + u * 16;
        float4 v = *(const float4*)(x + (size_t)(bi * 64 + r) * DIN + bj * 64 + c4 * 4);
        ushort4 o; o.x = f2bf(v.x); o.y = f2bf(v.y); o.z = f2bf(v.z); o.w = f2bf(v.w);
        *(ushort4*)(xbf + (size_t)(bi * 64 + r) * DIN + bj * 64 + c4 * 4) = o;
        *(ushort4*)&tile[r][c4 * 4] = o;
    }
    __syncthreads();
    // gather phase: thread owns tile-col c, row-quarter rq; writes 16 n-values of xT[k][n]
    int c = t >> 2, rq = t & 3;
    union { unsigned short us[16]; uint4 v4[2]; } g;
    #pragma unroll
    for (int i = 0; i < 16; ++i) g.us[i] = tile[rq * 16 + i][c];
    uint4* dT = (uint4*)(xT + (size_t)(bj * 64 + c) * NTOK + bi * 64 + rq * 16);
    dT[0] = g.v4[0];
    dT[1] = g.v4[1];
}

// =====================================================================================
// 256x256 / BK=64 / 8-wave / 8-phase GEMM mainloop (m201-style template, plain HIP).
// NT layout: C[row, col] = sum_k A[row, k] * B[col, k], both A,B bf16 row-major ld=4096.
// LDS: A dbuf [2][256][64] @ 0, B dbuf [2][256][64] @ 32768 ushorts (128 KiB).
// Bank swizzle: 16B chunk at (row, cc) stored at slot cc ^ (row & 7); applied to the
// per-lane GLOBAL source (global_load_lds dest stays linear) and to ds_read addresses.
// vmcnt discipline: counted vmcnt(4) at phases 4 and 8 only; vmcnt(0) only last iter.
// =====================================================================================
#define LDHALF 8192          // ushorts per 128-row half-tile
#define LDBUF  16384         // ushorts per 256-row dbuf buffer
#define B_BASE 32768         // ushort offset of B region

#define BAR()   __builtin_amdgcn_s_barrier()
#define LGKM0() do { asm volatile("s_waitcnt lgkmcnt(0)" ::: "memory"); \
                     __builtin_amdgcn_sched_barrier(0); } while (0)
#define VM(n_)  asm volatile("s_waitcnt vmcnt(" #n_ ")" ::: "memory")

#define STG(gp_, kt_, h_, buf_, reg_) do { \
    const unsigned short* gb_ = (gp_) + ((size_t)(h_) * 128) * 4096 + (size_t)(kt_) * 64; \
    async_copy16(gb_ + soff0, lds + (reg_) + (buf_) * LDBUF + (h_) * LDHALF + tid * 8); \
    async_copy16(gb_ + soff1, lds + (reg_) + (buf_) * LDBUF + (h_) * LDHALF + 4096 + tid * 8); \
  } while (0)

#define LDA4(rh_, buf_) { \
    _Pragma("unroll") for (int f = 0; f < 4; ++f) { \
      int ro_ = (buf_) * LDBUF + aOff + ((rh_) * 64 + f * 16) * 64; \
      a[f][0] = *(const bf16x8*)&lds[ro_ + swz0]; \
      a[f][1] = *(const bf16x8*)&lds[ro_ + swz1]; \
    } }

#define LDB2(bn_, ch_, buf_) { \
    _Pragma("unroll") for (int j = 0; j < 2; ++j) { \
      int ro_ = B_BASE + (buf_) * LDBUF + bOff + ((ch_) * 32 + j * 16) * 64; \
      bn_[j][0] = *(const bf16x8*)&lds[ro_ + swz0]; \
      bn_[j][1] = *(const bf16x8*)&lds[ro_ + swz1]; \
    } }

#define MFMAQ(rh_, bn_, ch_) { \
    _Pragma("unroll") for (int f = 0; f < 4; ++f) \
    _Pragma("unroll") for (int j = 0; j < 2; ++j) { \
      acc[(rh_)*4+f][(ch_)*2+j] = __builtin_amdgcn_mfma_f32_16x16x32_bf16( \
          a[f][0], bn_[j][0], acc[(rh_)*4+f][(ch_)*2+j], 0, 0, 0); \
      acc[(rh_)*4+f][(ch_)*2+j] = __builtin_amdgcn_mfma_f32_16x16x32_bf16( \
          a[f][1], bn_[j][1], acc[(rh_)*4+f][(ch_)*2+j], 0, 0, 0); \
    } }

__device__ __forceinline__ void gemm256_loop(const unsigned short* __restrict__ gAb,
                                             const unsigned short* __restrict__ gBb,
                                             unsigned short* lds, f32x4 (&acc)[8][4],
                                             int tid) {
    const int l16 = tid & 15, q = (tid >> 4) & 3, wid = tid >> 6;
    const int wr = wid >> 2, wc = wid & 3;
    const int swz0 = ((q) ^ (l16 & 7)) << 3;        // ks=0: cc = q
    const int swz1 = ((4 + q) ^ (l16 & 7)) << 3;    // ks=1: cc = 4+q
    const int aOff = (wr * 128 + l16) * 64;
    const int bOff = (wc * 64 + l16) * 64;
    // staging source offsets: chunk d = p*512+tid; row = d>>3, slot s = d&7,
    // logical chunk cc = s ^ (row&7)  (involution matches read-side XOR)
    const int soff0 = (tid >> 3) * 4096 + (((tid & 7) ^ ((tid >> 3) & 7)) << 3);
    const int soff1 = soff0 + 64 * 4096;

    bf16x8 a[4][2], b0[2][2], b1[2][2];
    #pragma unroll
    for (int i = 0; i < 8; ++i)
        #pragma unroll
        for (int j = 0; j < 4; ++j) acc[i][j] = (f32x4){0.f, 0.f, 0.f, 0.f};

    // prologue: kt0 (buf0) fully, kt1.B halves (buf1); allow kt1.B in flight
    STG(gAb, 0, 0, 0, 0);       STG(gAb, 0, 1, 0, 0);
    STG(gBb, 0, 0, 0, B_BASE);  STG(gBb, 0, 1, 0, B_BASE);
    STG(gBb, 1, 0, 1, B_BASE);  STG(gBb, 1, 1, 1, B_BASE);
    VM(4);
    BAR();

    #pragma unroll 1
    for (int i = 0; i < 32; ++i) {          // K-tiles 2i (buf0), 2i+1 (buf1)
        const bool nl = (i < 31);
        // ---- P1: Q(rh0,ch0) of kt ---- stage (kt+1).A0 -> buf1
        LDA4(0, 0); LDB2(b0, 0, 0);
        STG(gAb, 2 * i + 1, 0, 1, 0);
        BAR(); LGKM0();
        __builtin_amdgcn_s_setprio(1); MFMAQ(0, b0, 0); __builtin_amdgcn_s_setprio(0);
        BAR();
        // ---- P2: Q(rh0,ch1) ---- stage (kt+1).A1 -> buf1
        LDB2(b1, 1, 0);
        STG(gAb, 2 * i + 1, 1, 1, 0);
        BAR(); LGKM0();
        __builtin_amdgcn_s_setprio(1); MFMAQ(0, b1, 1); __builtin_amdgcn_s_setprio(0);
        BAR();
        // ---- P3: Q(rh1,ch0) ---- stage (kt+2).B0 -> buf0
        LDA4(1, 0);
        if (nl) STG(gBb, 2 * i + 2, 0, 0, B_BASE);
        BAR(); LGKM0();
        __builtin_amdgcn_s_setprio(1); MFMAQ(1, b0, 0); __builtin_amdgcn_s_setprio(0);
        BAR();
        // ---- P4: Q(rh1,ch1) ---- stage (kt+2).B1 -> buf0; K-tile boundary vmcnt
        if (nl) STG(gBb, 2 * i + 2, 1, 0, B_BASE);
        BAR();
        __builtin_amdgcn_s_setprio(1); MFMAQ(1, b1, 1); __builtin_amdgcn_s_setprio(0);
        if (nl) { VM(4); } else { VM(0); }   // last iter: stages skipped -> full drain
        BAR();
        // ---- P5: Q(rh0,ch0) of kt+1 (buf1) ---- stage (kt+2).A0 -> buf0
        LDA4(0, 1); LDB2(b0, 0, 1);
        if (nl) STG(gAb, 2 * i + 2, 0, 0, 0);
        BAR(); LGKM0();
        __builtin_amdgcn_s_setprio(1); MFMAQ(0, b0, 0); __builtin_amdgcn_s_setprio(0);
        BAR();
        // ---- P6 ---- stage (kt+2).A1 -> buf0
        LDB2(b1, 1, 1);
        if (nl) STG(gAb, 2 * i + 2, 1, 0, 0);
        BAR(); LGKM0();
        __builtin_amdgcn_s_setprio(1); MFMAQ(0, b1, 1); __builtin_amdgcn_s_setprio(0);
        BAR();
        // ---- P7 ---- stage (kt+3).B0 -> buf1
        LDA4(1, 1);
        if (nl) STG(gBb, 2 * i + 3, 0, 1, B_BASE);
        BAR(); LGKM0();
        __builtin_amdgcn_s_setprio(1); MFMAQ(1, b0, 0); __builtin_amdgcn_s_setprio(0);
        BAR();
        // ---- P8 ---- stage (kt+3).B1 -> buf1; K-tile boundary vmcnt
        if (nl) STG(gBb, 2 * i + 3, 1, 1, B_BASE);
        BAR();
        __builtin_amdgcn_s_setprio(1); MFMAQ(1, b1, 1); __builtin_amdgcn_s_setprio(0);
        if (nl) VM(4);
        BAR();
    }
}

// ---------------- GEMM1: y[n,m] = sum_k xbf[n,k]*weff[m,k]; epilogue y fp32 + relu^T bf16 ----
__launch_bounds__(512, 2)
__global__ void gemm1_kernel(const unsigned short* __restrict__ xbf, const unsigned short* __restrict__ weff,
                             float* __restrict__ y, unsigned short* __restrict__ yactT) {
    extern __shared__ unsigned short lds[];
    int tid = threadIdx.x;
    int bid = blockIdx.x;
    int swz = ((bid & 7) << 5) | (bid >> 3);        // XCD-aware bijective swizzle (256 wgs)
    int rowBase = (swz >> 4) * 256;                  // n
    int colBase = (swz & 15) * 256;                  // m

    f32x4 acc[8][4];
    gemm256_loop(xbf + (size_t)rowBase * 4096, weff + (size_t)colBase * 4096, lds, acc, tid);

    const int l16 = tid & 15, q = (tid >> 4) & 3, wid = tid >> 6;
    const int wr = wid >> 2, wc = wid & 3;

    // y fp32 store + relu-transpose staged in LDS (256 x 264-pad, reuses staging LDS)
    const int TSTR = 264;
    #pragma unroll
    for (int fi = 0; fi < 8; ++fi) {
        int rl = wr * 128 + fi * 16 + q * 4;
        #pragma unroll
        for (int fj = 0; fj < 4; ++fj) {
            int cl = wc * 64 + fj * 16 + l16;
            #pragma unroll
            for (int r = 0; r < 4; ++r) {
                float v = acc[fi][fj][r];
                y[(size_t)(rowBase + rl + r) * DOUT + colBase + cl] = v;
                lds[cl * TSTR + rl + r] = f2bf(fmaxf(v, 0.0f));
            }
        }
    }
    __syncthreads();
    // coalesced write of yactT[m][n]: 8 threads per m-row, 4 passes of 64 rows
    int mrow = tid >> 3, cchunk = tid & 7;
    #pragma unroll
    for (int pass = 0; pass < 4; ++pass) {
        int mm = pass * 64 + mrow;
        const uint4* src = (const uint4*)(lds + mm * TSTR);
        uint4* dst = (uint4*)(yactT + (size_t)(colBase + mm) * NTOK + rowBase);
        #pragma unroll
        for (int g = 0; g < 4; ++g) dst[cchunk + g * 8] = src[cchunk + g * 8];
    }
}

// ---------------- GEMM2 (+fused homeostatic finalize via cooperative grid sync) -------------
// nf_pre[m,k] = 0.95*fast + 0.05*(sum_n yactT[m,n]*xT[k,n])/4096; norm over all nf; then
// outFast = nf*s, outSlow = 0.99*slow + 0.01*outFast. nf stays in acc registers across sync.
__launch_bounds__(512, 2)
__global__ void gemm2_kernel(const unsigned short* __restrict__ yactT, const unsigned short* __restrict__ xT,
                             const float* __restrict__ fast, const float* __restrict__ slow,
                             float* __restrict__ outFast, float* __restrict__ outSlow,
                             float* __restrict__ norm2) {
    extern __shared__ unsigned short lds[];
    int tid = threadIdx.x;
    int bid = blockIdx.x;
    int swz = ((bid & 7) << 5) | (bid >> 3);
    int rowBase = (swz >> 4) * 256;                  // m
    int colBase = (swz & 15) * 256;                  // k

    f32x4 acc[8][4];
    gemm256_loop(yactT + (size_t)rowBase * 4096, xT + (size_t)colBase * 4096, lds, acc, tid);

    const int l16 = tid & 15, q = (tid >> 4) & 3, wid = tid >> 6;
    const int wr = wid >> 2, wc = wid & 3;
    const int lane = tid & 63;

    // nf in-place into acc + block norm partial
    float lsum = 0.f;
    #pragma unroll
    for (int fi = 0; fi < 8; ++fi) {
        int rg = rowBase + wr * 128 + fi * 16 + q * 4;
        #pragma unroll
        for (int fj = 0; fj < 4; ++fj) {
            int cg = colBase + wc * 64 + fj * 16 + l16;
            #pragma unroll
            for (int r = 0; r < 4; ++r) {
                float d = acc[fi][fj][r] * (1.0f / 4096.0f);
                float nf = 0.95f * fast[(size_t)(rg + r) * DIN + cg] + 0.05f * d;
                acc[fi][fj][r] = nf;
                lsum += nf * nf;
            }
        }
    }
    for (int o = 32; o > 0; o >>= 1) lsum += __shfl_down(lsum, o);
    float* redbuf = (float*)lds;
    __syncthreads();
    if (lane == 0) redbuf[wid] = lsum;
    __syncthreads();
    if (tid == 0) {
        float bs = 0.f;
        #pragma unroll
        for (int k2 = 0; k2 < 8; ++k2) bs += redbuf[k2];
        atomicAdd(norm2, bs);
    }
    __threadfence();
    cg::this_grid().sync();
    if (tid == 0) redbuf[0] = atomicAdd(norm2, 0.0f);   // device-scope read of final norm
    __syncthreads();
    float n = sqrtf(redbuf[0]);
    float s = (n > 5.0f) ? 5.0f / (n + 1e-6f) : 1.0f;

    #pragma unroll
    for (int fi = 0; fi < 8; ++fi) {
        int rg = rowBase + wr * 128 + fi * 16 + q * 4;
        #pragma unroll
        for (int fj = 0; fj < 4; ++fj) {
            int cg = colBase + wc * 64 + fj * 16 + l16;
            #pragma unroll
            for (int r = 0; r < 4; ++r) {
                size_t idx = (size_t)(rg + r) * DIN + cg;
                float f = acc[fi][fj][r] * s;
                outFast[idx] = f;
                outSlow[idx] = 0.99f * slow[idx] + 0.01f * f;
            }
        }
    }
}

extern "C" void kernel_launch(void* const* d_in, const int* in_sizes, int n_in,
                              void* d_out, int out_size, void* d_ws, size_t ws_size,
                              hipStream_t stream) {
    const float* x    = (const float*)d_in[0];
    const float* w    = (const float*)d_in[1];
    const float* fast = (const float*)d_in[2];
    const float* slow = (const float*)d_in[3];
    float* y       = (float*)d_out;
    float* outFast = y + (size_t)NTOK * DOUT;
    float* outSlow = outFast + (size_t)DOUT * DIN;

    char* ws = (char*)d_ws;
    float* norm2 = (float*)ws;                                 // 4 B (+pad to 256)
    unsigned short* weff  = (unsigned short*)(ws + 256);
    unsigned short* xbf   = weff + (size_t)DOUT * DIN;
    unsigned short* xT    = xbf + (size_t)NTOK * DIN;
    unsigned short* yactT = xT + (size_t)DIN * NTOK;
    // total ws use: 256 B + 4 * 33.55 MB ≈ 134 MB

    static bool s_attr = false;
    if (!s_attr) {
        hipFuncSetAttribute((const void*)gemm1_kernel,
                            hipFuncAttributeMaxDynamicSharedMemorySize, 135168);
        hipFuncSetAttribute((const void*)gemm2_kernel,
                            hipFuncAttributeMaxDynamicSharedMemorySize, 131072);
        s_attr = true;
    }

    hipMemsetAsync(norm2, 0, sizeof(float), stream);
    weff_kernel<<<4096, 256, 0, stream>>>(w, fast, slow, weff);
    transpose_kernel<<<dim3(64, 64), dim3(256), 0, stream>>>(x, xbf, xT);
    gemm1_kernel<<<256, 512, 135168, stream>>>(xbf, weff, y, yactT);
    void* g2args[] = { (void*)&yactT, (void*)&xT, (void*)&fast, (void*)&slow,
                       (void*)&outFast, (void*)&outSlow, (void*)&norm2 };
    hipLaunchCooperativeKernel((const void*)gemm2_kernel, dim3(256), dim3(512),
                               g2args, 131072, stream);
}

// Round 3
// 654.639 us; speedup vs baseline: 1.1163x; 1.1163x over previous
//
#include <hip/hip_runtime.h>

#define NTOK 4096
#define DIN  4096
#define DOUT 4096

typedef short bf16x8 __attribute__((ext_vector_type(8)));
typedef float f32x4  __attribute__((ext_vector_type(4)));

__device__ __forceinline__ unsigned short f2bf(float f) {
    union { float f; unsigned u; } v; v.f = f;
    unsigned r = v.u + 0x7FFFu + ((v.u >> 16) & 1u);
    return (unsigned short)(r >> 16);
}

__device__ __forceinline__ void async_copy16(const void* g, void* l) {
    __builtin_amdgcn_global_load_lds(
        (const __attribute__((address_space(1))) unsigned int*)g,
        (__attribute__((address_space(3))) unsigned int*)l, 16, 0, 0);
}

// ---------------- fused scale + w_eff (no fp64 divide: |w| >= 0.5*sc comparison) -------------
// clip(rint(w/sc),-1,1)*sc  ==  (|w| >= 0.5*sc) ? copysign(sc, w) : 0   for sc > 0
// (identical in fp64 except exact ties, measure-zero). One block per row; w kept in registers.
__global__ void weff_kernel(const float* __restrict__ w, const float* __restrict__ fast,
                            const float* __restrict__ slow, unsigned short* __restrict__ weff) {
    int row = blockIdx.x;
    int t = threadIdx.x;                                  // 256 threads
    const float4* wr = (const float4*)(w + (size_t)row * DIN);
    const float4* fr = (const float4*)(fast + (size_t)row * DIN);
    const float4* sr = (const float4*)(slow + (size_t)row * DIN);
    ushort4* ow = (ushort4*)(weff + (size_t)row * DIN);

    float4 wv[4];
    double s = 0.0;
    #pragma unroll
    for (int u = 0; u < 4; ++u) {
        wv[u] = wr[t + u * 256];
        s += (double)fabsf(wv[u].x) + (double)fabsf(wv[u].y)
           + (double)fabsf(wv[u].z) + (double)fabsf(wv[u].w);
    }
    for (int o = 32; o > 0; o >>= 1) s += __shfl_down(s, o);
    __shared__ double part[4];
    __shared__ double scLds;
    int wave = t >> 6, lane = t & 63;
    if (lane == 0) part[wave] = s;
    __syncthreads();
    if (t == 0) scLds = fmax((part[0] + part[1] + part[2] + part[3]) * (1.0 / DIN), 1e-5);
    __syncthreads();
    double scd = scLds;
    double hs = 0.5 * scd;

    #pragma unroll
    for (int u = 0; u < 4; ++u) {
        float4 fv = fr[t + u * 256];
        float4 sv = sr[t + u * 256];
        float4 wq = wv[u];
        ushort4 o;
        o.x = f2bf((float)((((double)fabsf(wq.x) >= hs) ? copysign(scd, (double)wq.x) : 0.0)
                           + 0.1 * (double)fv.x + 0.05 * (double)sv.x));
        o.y = f2bf((float)((((double)fabsf(wq.y) >= hs) ? copysign(scd, (double)wq.y) : 0.0)
                           + 0.1 * (double)fv.y + 0.05 * (double)sv.y));
        o.z = f2bf((float)((((double)fabsf(wq.z) >= hs) ? copysign(scd, (double)wq.z) : 0.0)
                           + 0.1 * (double)fv.z + 0.05 * (double)sv.z));
        o.w = f2bf((float)((((double)fabsf(wq.w) >= hs) ? copysign(scd, (double)wq.w) : 0.0)
                           + 0.1 * (double)fv.w + 0.05 * (double)sv.w));
        ow[t + u * 256] = o;
    }
}

// ---------------- x -> x_bf16 (row-major) + xT bf16, vectorized 64x64 tiles -----------------
__global__ void transpose_kernel(const float* __restrict__ x, unsigned short* __restrict__ xbf,
                                 unsigned short* __restrict__ xT) {
    __shared__ unsigned short tile[64][72];
    int bi = blockIdx.y, bj = blockIdx.x;   // 64-row x 64-col tile
    int t = threadIdx.x;                    // 256
    int c4 = t & 15, r0 = t >> 4;
    #pragma unroll
    for (int u = 0; u < 4; ++u) {
        int r = r0 + u * 16;
        float4 v = *(const float4*)(x + (size_t)(bi * 64 + r) * DIN + bj * 64 + c4 * 4);
        ushort4 o; o.x = f2bf(v.x); o.y = f2bf(v.y); o.z = f2bf(v.z); o.w = f2bf(v.w);
        *(ushort4*)(xbf + (size_t)(bi * 64 + r) * DIN + bj * 64 + c4 * 4) = o;
        *(ushort4*)&tile[r][c4 * 4] = o;
    }
    __syncthreads();
    int c = t >> 2, rq = t & 3;
    union { unsigned short us[16]; uint4 v4[2]; } g;
    #pragma unroll
    for (int i = 0; i < 16; ++i) g.us[i] = tile[rq * 16 + i][c];
    uint4* dT = (uint4*)(xT + (size_t)(bj * 64 + c) * NTOK + bi * 64 + rq * 16);
    dT[0] = g.v4[0];
    dT[1] = g.v4[1];
}

// =====================================================================================
// 256x256 / BK=64 / 8-wave / 8-phase GEMM mainloop (m201-style template, plain HIP).
// NT layout: C[row, col] = sum_k A[row, k] * B[col, k], both A,B bf16 row-major ld=4096.
// LDS: A dbuf [2][256][64] @ 0, B dbuf [2][256][64] @ 32768 ushorts (128 KiB).
// Bank swizzle: 16B chunk at (row, cc) stored at slot cc ^ (row & 7); applied to the
// per-lane GLOBAL source (global_load_lds dest stays linear) and to ds_read addresses.
// vmcnt discipline: counted vmcnt(4) at phases 4 and 8 only; vmcnt(0) only last iter.
// =====================================================================================
#define LDHALF 8192          // ushorts per 128-row half-tile
#define LDBUF  16384         // ushorts per 256-row dbuf buffer
#define B_BASE 32768         // ushort offset of B region

#define BAR()   __builtin_amdgcn_s_barrier()
#define LGKM0() do { asm volatile("s_waitcnt lgkmcnt(0)" ::: "memory"); \
                     __builtin_amdgcn_sched_barrier(0); } while (0)
#define VM(n_)  asm volatile("s_waitcnt vmcnt(" #n_ ")" ::: "memory")

#define STG(gp_, kt_, h_, buf_, reg_) do { \
    const unsigned short* gb_ = (gp_) + ((size_t)(h_) * 128) * 4096 + (size_t)(kt_) * 64; \
    async_copy16(gb_ + soff0, lds + (reg_) + (buf_) * LDBUF + (h_) * LDHALF + tid * 8); \
    async_copy16(gb_ + soff1, lds + (reg_) + (buf_) * LDBUF + (h_) * LDHALF + 4096 + tid * 8); \
  } while (0)

#define LDA4(rh_, buf_) { \
    _Pragma("unroll") for (int f = 0; f < 4; ++f) { \
      int ro_ = (buf_) * LDBUF + aOff + ((rh_) * 64 + f * 16) * 64; \
      a[f][0] = *(const bf16x8*)&lds[ro_ + swz0]; \
      a[f][1] = *(const bf16x8*)&lds[ro_ + swz1]; \
    } }

#define LDB2(bn_, ch_, buf_) { \
    _Pragma("unroll") for (int j = 0; j < 2; ++j) { \
      int ro_ = B_BASE + (buf_) * LDBUF + bOff + ((ch_) * 32 + j * 16) * 64; \
      bn_[j][0] = *(const bf16x8*)&lds[ro_ + swz0]; \
      bn_[j][1] = *(const bf16x8*)&lds[ro_ + swz1]; \
    } }

#define MFMAQ(rh_, bn_, ch_) { \
    _Pragma("unroll") for (int f = 0; f < 4; ++f) \
    _Pragma("unroll") for (int j = 0; j < 2; ++j) { \
      acc[(rh_)*4+f][(ch_)*2+j] = __builtin_amdgcn_mfma_f32_16x16x32_bf16( \
          a[f][0], bn_[j][0], acc[(rh_)*4+f][(ch_)*2+j], 0, 0, 0); \
      acc[(rh_)*4+f][(ch_)*2+j] = __builtin_amdgcn_mfma_f32_16x16x32_bf16( \
          a[f][1], bn_[j][1], acc[(rh_)*4+f][(ch_)*2+j], 0, 0, 0); \
    } }

__device__ __forceinline__ void gemm256_loop(const unsigned short* __restrict__ gAb,
                                             const unsigned short* __restrict__ gBb,
                                             unsigned short* lds, f32x4 (&acc)[8][4],
                                             int tid) {
    const int l16 = tid & 15, q = (tid >> 4) & 3, wid = tid >> 6;
    const int wr = wid >> 2, wc = wid & 3;
    const int swz0 = ((q) ^ (l16 & 7)) << 3;        // ks=0: cc = q
    const int swz1 = ((4 + q) ^ (l16 & 7)) << 3;    // ks=1: cc = 4+q
    const int aOff = (wr * 128 + l16) * 64;
    const int bOff = (wc * 64 + l16) * 64;
    const int soff0 = (tid >> 3) * 4096 + (((tid & 7) ^ ((tid >> 3) & 7)) << 3);
    const int soff1 = soff0 + 64 * 4096;

    bf16x8 a[4][2], b0[2][2], b1[2][2];
    #pragma unroll
    for (int i = 0; i < 8; ++i)
        #pragma unroll
        for (int j = 0; j < 4; ++j) acc[i][j] = (f32x4){0.f, 0.f, 0.f, 0.f};

    // prologue: kt0 (buf0) fully, kt1.B halves (buf1); allow kt1.B in flight
    STG(gAb, 0, 0, 0, 0);       STG(gAb, 0, 1, 0, 0);
    STG(gBb, 0, 0, 0, B_BASE);  STG(gBb, 0, 1, 0, B_BASE);
    STG(gBb, 1, 0, 1, B_BASE);  STG(gBb, 1, 1, 1, B_BASE);
    VM(4);
    BAR();

    #pragma unroll 1
    for (int i = 0; i < 32; ++i) {          // K-tiles 2i (buf0), 2i+1 (buf1)
        const bool nl = (i < 31);
        // ---- P1: Q(rh0,ch0) of kt ---- stage (kt+1).A0 -> buf1
        LDA4(0, 0); LDB2(b0, 0, 0);
        STG(gAb, 2 * i + 1, 0, 1, 0);
        BAR(); LGKM0();
        __builtin_amdgcn_s_setprio(1); MFMAQ(0, b0, 0); __builtin_amdgcn_s_setprio(0);
        BAR();
        // ---- P2: Q(rh0,ch1) ---- stage (kt+1).A1 -> buf1
        LDB2(b1, 1, 0);
        STG(gAb, 2 * i + 1, 1, 1, 0);
        BAR(); LGKM0();
        __builtin_amdgcn_s_setprio(1); MFMAQ(0, b1, 1); __builtin_amdgcn_s_setprio(0);
        BAR();
        // ---- P3: Q(rh1,ch0) ---- stage (kt+2).B0 -> buf0
        LDA4(1, 0);
        if (nl) STG(gBb, 2 * i + 2, 0, 0, B_BASE);
        BAR(); LGKM0();
        __builtin_amdgcn_s_setprio(1); MFMAQ(1, b0, 0); __builtin_amdgcn_s_setprio(0);
        BAR();
        // ---- P4: Q(rh1,ch1) ---- stage (kt+2).B1 -> buf0; K-tile boundary vmcnt
        if (nl) STG(gBb, 2 * i + 2, 1, 0, B_BASE);
        BAR();
        __builtin_amdgcn_s_setprio(1); MFMAQ(1, b1, 1); __builtin_amdgcn_s_setprio(0);
        if (nl) { VM(4); } else { VM(0); }   // last iter: stages skipped -> full drain
        BAR();
        // ---- P5: Q(rh0,ch0) of kt+1 (buf1) ---- stage (kt+2).A0 -> buf0
        LDA4(0, 1); LDB2(b0, 0, 1);
        if (nl) STG(gAb, 2 * i + 2, 0, 0, 0);
        BAR(); LGKM0();
        __builtin_amdgcn_s_setprio(1); MFMAQ(0, b0, 0); __builtin_amdgcn_s_setprio(0);
        BAR();
        // ---- P6 ---- stage (kt+2).A1 -> buf0
        LDB2(b1, 1, 1);
        if (nl) STG(gAb, 2 * i + 2, 1, 0, 0);
        BAR(); LGKM0();
        __builtin_amdgcn_s_setprio(1); MFMAQ(0, b1, 1); __builtin_amdgcn_s_setprio(0);
        BAR();
        // ---- P7 ---- stage (kt+3).B0 -> buf1
        LDA4(1, 1);
        if (nl) STG(gBb, 2 * i + 3, 0, 1, B_BASE);
        BAR(); LGKM0();
        __builtin_amdgcn_s_setprio(1); MFMAQ(1, b0, 0); __builtin_amdgcn_s_setprio(0);
        BAR();
        // ---- P8 ---- stage (kt+3).B1 -> buf1; K-tile boundary vmcnt
        if (nl) STG(gBb, 2 * i + 3, 1, 1, B_BASE);
        BAR();
        __builtin_amdgcn_s_setprio(1); MFMAQ(1, b1, 1); __builtin_amdgcn_s_setprio(0);
        if (nl) VM(4);
        BAR();
    }
}

// ---------------- GEMM1: y[n,m] = sum_k xbf[n,k]*weff[m,k]; epilogue y fp32 + relu^T bf16 ----
__launch_bounds__(512, 2)
__global__ void gemm1_kernel(const unsigned short* __restrict__ xbf, const unsigned short* __restrict__ weff,
                             float* __restrict__ y, unsigned short* __restrict__ yactT) {
    extern __shared__ unsigned short lds[];
    int tid = threadIdx.x;
    int bid = blockIdx.x;
    int swz = ((bid & 7) << 5) | (bid >> 3);        // XCD-aware bijective swizzle (256 wgs)
    int rowBase = (swz >> 4) * 256;                  // n
    int colBase = (swz & 15) * 256;                  // m

    f32x4 acc[8][4];
    gemm256_loop(xbf + (size_t)rowBase * 4096, weff + (size_t)colBase * 4096, lds, acc, tid);

    const int l16 = tid & 15, q = (tid >> 4) & 3, wid = tid >> 6;
    const int wr = wid >> 2, wc = wid & 3;

    // y fp32 store (nontemporal: write-once stream) + relu-transpose staged in LDS
    const int TSTR = 264;
    #pragma unroll
    for (int fi = 0; fi < 8; ++fi) {
        int rl = wr * 128 + fi * 16 + q * 4;
        #pragma unroll
        for (int fj = 0; fj < 4; ++fj) {
            int cl = wc * 64 + fj * 16 + l16;
            #pragma unroll
            for (int r = 0; r < 4; ++r) {
                float v = acc[fi][fj][r];
                __builtin_nontemporal_store(v, &y[(size_t)(rowBase + rl + r) * DOUT + colBase + cl]);
                lds[cl * TSTR + rl + r] = f2bf(fmaxf(v, 0.0f));
            }
        }
    }
    __syncthreads();
    // coalesced write of yactT[m][n]: 8 threads per m-row, 4 passes of 64 rows
    int mrow = tid >> 3, cchunk = tid & 7;
    #pragma unroll
    for (int pass = 0; pass < 4; ++pass) {
        int mm = pass * 64 + mrow;
        const uint4* src = (const uint4*)(lds + mm * TSTR);
        uint4* dst = (uint4*)(yactT + (size_t)(colBase + mm) * NTOK + rowBase);
        #pragma unroll
        for (int g = 0; g < 4; ++g) dst[cchunk + g * 8] = src[cchunk + g * 8];
    }
}

// ---------------- GEMM2: nf_pre[m,k] = 0.95*fast + 0.05*(sum_n yactT[m,n]*xT[k,n])/4096 -----
__launch_bounds__(512, 2)
__global__ void gemm2_kernel(const unsigned short* __restrict__ yactT, const unsigned short* __restrict__ xT,
                             const float* __restrict__ fast, float* __restrict__ outFast,
                             float* __restrict__ norm2) {
    extern __shared__ unsigned short lds[];
    int tid = threadIdx.x;
    int bid = blockIdx.x;
    int swz = ((bid & 7) << 5) | (bid >> 3);
    int rowBase = (swz >> 4) * 256;                  // m
    int colBase = (swz & 15) * 256;                  // k

    f32x4 acc[8][4];
    gemm256_loop(yactT + (size_t)rowBase * 4096, xT + (size_t)colBase * 4096, lds, acc, tid);

    const int l16 = tid & 15, q = (tid >> 4) & 3, wid = tid >> 6;
    const int wr = wid >> 2, wc = wid & 3;
    const int lane = tid & 63;

    float lsum = 0.f;
    #pragma unroll
    for (int fi = 0; fi < 8; ++fi) {
        int rg = rowBase + wr * 128 + fi * 16 + q * 4;
        #pragma unroll
        for (int fj = 0; fj < 4; ++fj) {
            int cg = colBase + wc * 64 + fj * 16 + l16;
            #pragma unroll
            for (int r = 0; r < 4; ++r) {
                float d = acc[fi][fj][r] * (1.0f / 4096.0f);
                float nf = 0.95f * fast[(size_t)(rg + r) * DIN + cg] + 0.05f * d;
                outFast[(size_t)(rg + r) * DIN + cg] = nf;
                lsum += nf * nf;
            }
        }
    }
    for (int o = 32; o > 0; o >>= 1) lsum += __shfl_down(lsum, o);
    float* redbuf = (float*)lds;
    __syncthreads();
    if (lane == 0) redbuf[wid] = lsum;
    __syncthreads();
    if (tid == 0) {
        float s = 0.f;
        #pragma unroll
        for (int k2 = 0; k2 < 8; ++k2) s += redbuf[k2];
        atomicAdd(norm2, s);
    }
}

// ---------------- finalize: homeostatic rescale + slow update ----------------
__global__ void finalize_kernel(const float* __restrict__ slow, float* __restrict__ outFast,
                                float* __restrict__ outSlow, const float* __restrict__ norm2) {
    float n = sqrtf(*norm2);
    float s = (n > 5.0f) ? 5.0f / (n + 1e-6f) : 1.0f;
    int i = blockIdx.x * 256 + threadIdx.x;          // float4 index
    float4 f = ((const float4*)outFast)[i];
    f.x *= s; f.y *= s; f.z *= s; f.w *= s;
    f32x4 fo = {f.x, f.y, f.z, f.w};
    __builtin_nontemporal_store(fo, (f32x4*)outFast + i);
    float4 sl = ((const float4*)slow)[i];
    f32x4 o;
    o[0] = 0.99f * sl.x + 0.01f * f.x;
    o[1] = 0.99f * sl.y + 0.01f * f.y;
    o[2] = 0.99f * sl.z + 0.01f * f.z;
    o[3] = 0.99f * sl.w + 0.01f * f.w;
    __builtin_nontemporal_store(o, (f32x4*)outSlow + i);
}

extern "C" void kernel_launch(void* const* d_in, const int* in_sizes, int n_in,
                              void* d_out, int out_size, void* d_ws, size_t ws_size,
                              hipStream_t stream) {
    const float* x    = (const float*)d_in[0];
    const float* w    = (const float*)d_in[1];
    const float* fast = (const float*)d_in[2];
    const float* slow = (const float*)d_in[3];
    float* y       = (float*)d_out;
    float* outFast = y + (size_t)NTOK * DOUT;
    float* outSlow = outFast + (size_t)DOUT * DIN;

    char* ws = (char*)d_ws;
    float* norm2 = (float*)ws;                                 // 4 B (+pad to 256)
    unsigned short* weff  = (unsigned short*)(ws + 256);
    unsigned short* xbf   = weff + (size_t)DOUT * DIN;
    unsigned short* xT    = xbf + (size_t)NTOK * DIN;
    unsigned short* yactT = xT + (size_t)DIN * NTOK;
    // total ws use: 256 B + 4 * 33.55 MB ≈ 134 MB

    static bool s_attr = false;
    if (!s_attr) {
        hipFuncSetAttribute((const void*)gemm1_kernel,
                            hipFuncAttributeMaxDynamicSharedMemorySize, 135168);
        hipFuncSetAttribute((const void*)gemm2_kernel,
                            hipFuncAttributeMaxDynamicSharedMemorySize, 131072);
        s_attr = true;
    }

    hipMemsetAsync(norm2, 0, sizeof(float), stream);
    weff_kernel<<<4096, 256, 0, stream>>>(w, fast, slow, weff);
    transpose_kernel<<<dim3(64, 64), dim3(256), 0, stream>>>(x, xbf, xT);
    gemm1_kernel<<<256, 512, 135168, stream>>>(xbf, weff, y, yactT);
    gemm2_kernel<<<256, 512, 131072, stream>>>(yactT, xT, fast, outFast, norm2);
    finalize_kernel<<<16384, 256, 0, stream>>>(slow, outFast, outSlow, norm2);
}